// Round 5
// baseline (284.802 us; speedup 1.0000x reference)
//
#include <hip/hip_runtime.h>
#include <hip/hip_bf16.h>
#include <stdint.h>

// Problem constants (from reference)
#define O_DIM   4096
#define I_DIM   2048
#define M_DENSE 8192
#define K_DENSE 4096
#define N_TOK   4096
#define K_ACT   2048

typedef __bf16 bf16x8 __attribute__((ext_vector_type(8)));
typedef float  f32x4  __attribute__((ext_vector_type(4)));

// round-to-nearest-even fp32 -> bf16 bits
__device__ __forceinline__ unsigned f2bf(float f) {
    unsigned u = __builtin_bit_cast(unsigned, f);
    return (u + 0x7FFFu + ((u >> 16) & 1u)) >> 16;
}

// async global->LDS, 16 bytes per lane; LDS dest = wave-uniform base + lane*16
__device__ __forceinline__ void load16(const unsigned short* g, unsigned short* l) {
    __builtin_amdgcn_global_load_lds(
        (__attribute__((address_space(1))) void*)(g),
        (__attribute__((address_space(3))) void*)(l),
        16, 0, 0);
}

// ---------------------------------------------------------------------------
// Merged prep:
//   blocks [0, O_DIM)            : decompress 2:4 weights -> A2 [O][K_ACT] bf16
//   blocks [O_DIM, O_DIM+4096)   : cast input fp32 -> Bbt bf16 (same layout)
//   blocks [O_DIM+4096, +4097)   : zero INACTIVE dense output rows
// R4: zero-branch nt stores use SCALAR u64 (global_store_dwordx2 nt) —
// defensive rewrite of R3's 16B-vector nt store after two container
// failures; same bytes, same no-RFO/no-L2-pollution semantics.
// ---------------------------------------------------------------------------
__global__ __launch_bounds__(256) void prep(const float* __restrict__ weight,
                                            const int* __restrict__ metadata,
                                            const int* __restrict__ idx,
                                            const float* __restrict__ input,
                                            const int* __restrict__ indices,
                                            uint4* __restrict__ A2,
                                            uint4* __restrict__ Bbt,
                                            unsigned long long* __restrict__ out2) {
    const int CAST_BLKS = (N_TOK * K_ACT / 8) / 256;   // 4096
    int bx = blockIdx.x;
    if (bx >= O_DIM + CAST_BLKS) {
        // ---- zero branch: block b zeroes rows in (indices[b-1], indices[b]) ----
        int b = bx - (O_DIM + CAST_BLKS);               // 0 .. O_DIM
        int lo = (b == 0) ? -1 : indices[b - 1];
        int hi = (b == O_DIM) ? M_DENSE : indices[b];
        for (int row = lo + 1; row < hi; ++row) {
            unsigned long long* dst = out2 + (size_t)row * (N_TOK / 2);
            for (int c = threadIdx.x; c < N_TOK / 2; c += 256)
                __builtin_nontemporal_store(0ull, dst + c);
        }
        return;
    }
    if (bx >= O_DIM) {
        // ---- cast branch: fp32 [N_TOK x K_ACT] -> bf16 bits ----
        int gid = (bx - O_DIM) * 256 + threadIdx.x;
        const float4* in = (const float4*)input;
        float4 a = in[2 * gid], b = in[2 * gid + 1];
        uint4 u;
        u.x = f2bf(a.x) | (f2bf(a.y) << 16);
        u.y = f2bf(a.z) | (f2bf(a.w) << 16);
        u.z = f2bf(b.x) | (f2bf(b.y) << 16);
        u.w = f2bf(b.z) | (f2bf(b.w) << 16);
        Bbt[gid] = u;                                   // re-read by gemm: keep cached
        return;
    }
    // ---- decompress branch: A2[o][j] = weight value for active col idx[j] ----
    __shared__ int   smeta[I_DIM];
    __shared__ float sw[I_DIM];
    int o = bx;
    const int4*   mrow = (const int4*)(metadata + (size_t)o * I_DIM);
    const float4* wrow = (const float4*)(weight + (size_t)o * I_DIM);
#pragma unroll
    for (int it = 0; it < I_DIM / 4 / 256; ++it) {
        int i = it * 256 + threadIdx.x;
        *(int4*)(smeta + i * 4) = mrow[i];
        *(float4*)(sw + i * 4)  = wrow[i];
    }
    __syncthreads();
    int j0 = threadIdx.x * 8;                            // 256 threads * 8 = K_ACT
    int4 c0 = *(const int4*)(idx + j0);
    int4 c1 = *(const int4*)(idx + j0 + 4);
    int cs[8] = {c0.x, c0.y, c0.z, c0.w, c1.x, c1.y, c1.z, c1.w};
    unsigned r[8];
#pragma unroll
    for (int u = 0; u < 8; ++u) {
        int c = cs[u];
        int g2 = (c >> 2) * 2;
        int pos = c & 3;
        int m0v = smeta[g2], m1v = smeta[g2 + 1];
        float v = (m0v == pos) ? sw[g2] : ((m1v == pos) ? sw[g2 + 1] : 0.0f);
        r[u] = f2bf(v);
    }
    uint4 packed;
    packed.x = r[0] | (r[1] << 16);
    packed.y = r[2] | (r[3] << 16);
    packed.z = r[4] | (r[5] << 16);
    packed.w = r[6] | (r[7] << 16);
    A2[((size_t)o * K_ACT + j0) >> 3] = packed;          // re-read by gemm: cached
}

// ---------------------------------------------------------------------------
// GEMM, 256x256 tile, 8 waves (2Mx4N), 8-phase counted-vmcnt schedule.
//   C[o][t] = sum_j A[o][j] * Bt[t][j];  rows scattered via indices[].
// K split into 64 tiles of 32. LDS = 4-slot ring per matrix; slot =
// [128 rows][8 phys 16B-slots].  FULL 3-bit slot swizzle (R1 post-mortem:
// 1-bit st_16x32 left banks 16-31 idle -> +4 conflict cyc per b128 read):
//   phys_slot = logical_slot ^ (row & 7)
// logical slots 0-3 = rows rr (k 0..31), 4-7 = rows rr+128 (k 0..31).
// Per wave-read, row r touches phys slots {quad}^(r&7): uniform 32B/bank,
// zero conflicts (R2: gemm8 dropped below the 82us fills => <82us).
// global_load_lds writes LDS linearly; SOURCE address carries the inverse
// swizzle (involution, both-sides rule): for the linear dest, row&7 ==
// (tid>>3)&7, so logical_slot = (tid&7) ^ ((tid>>3)&7), wave/inst-invariant.
// Pipeline: prefetch 3 K-tiles ahead; 4 loads/thread per K-tile (2/phase);
// vmcnt(8) once per K-tile retires exactly the next tile's 4 loads (FIFO).
// Tail wraps prefetch to dummy tiles so counts/barriers stay uniform.
// Per phase: {ds_read subtile || 2 global_load_lds -> s_barrier ->
// lgkmcnt(0) -> setprio(1) -> 16 MFMA -> setprio(0) -> s_barrier}.
// R3/R4: epilogue stores NONTEMPORAL (scalar float) — kills the 64MB RFO
// on output lines (R2 FETCH 78.4MB vs ~32MB compulsory; predicted ~50MB).
// ---------------------------------------------------------------------------
__global__ __launch_bounds__(512, 2) void gemm8(
        const unsigned short* __restrict__ A,
        const unsigned short* __restrict__ Bt,
        const int* __restrict__ indices,
        float* __restrict__ out) {
    constexpr int N = N_TOK, K = K_ACT;
    constexpr int NT = K / 32;                       // 64 K-tiles
    __shared__ alignas(16) unsigned short lds[65536]; // 128 KB: A slots | B slots
    __shared__ int sidx[256];

    const int tid  = threadIdx.x;                    // 0..511
    const int wave = tid >> 6;                       // 0..7
    const int lane = tid & 63;
    const int quad = lane >> 4;
    const int lr   = lane & 15;
    const int wm   = (wave >> 2) * 128;              // wave tile: 128x64
    const int wn   = (wave & 3) * 64;

    // XCD-aware mapping: 256 blocks, 8 XCDs, 32 blocks/XCD; each XCD owns an
    // n-pair (2MB B-panel ~ L2-resident) and streams A m-panels.
    const int bid = blockIdx.x;
    const int xcd = bid & 7;
    const int j   = bid >> 3;                        // 0..31
    const int m0  = (j & 15) * 256;
    const int n0  = (xcd * 2 + (j >> 4)) * 256;

    // ---- staging source (inverse-swizzled global) ----
    // linear dest of thread t, inst i: LDS row rr = i*64 + (tid>>3),
    // phys slot = tid&7; rr&7 == (tid>>3)&7 for all waves/insts.
    const int sr_ = tid >> 3;                        // 0..63
    const int ls_ = (tid & 7) ^ (sr_ & 7);           // logical slot 0..7
    const int rh_ = ls_ >> 2;                        // row-half select
    const int ke_ = (ls_ & 3) * 8;                   // k-element 0..31
    const unsigned short* gA0 = A  + (size_t)(m0 + sr_ +      rh_ * 128) * K + ke_;
    const unsigned short* gA1 = A  + (size_t)(m0 + sr_ + 64 + rh_ * 128) * K + ke_;
    const unsigned short* gB0 = Bt + (size_t)(n0 + sr_ +      rh_ * 128) * K + ke_;
    const unsigned short* gB1 = Bt + (size_t)(n0 + sr_ + 64 + rh_ * 128) * K + ke_;
    unsigned short* dA = lds + wave * 512;           // + slot*8192 (+4096 inst1)
    unsigned short* dB = lds + 32768 + wave * 512;

    // ---- ds_read byte offsets (swizzled). mi/ni stride 2048 and the 8192
    // phase-1 offset are swizzle-invariant (16-row strides keep row&7). ----
    const int laA = wm + lr, srA = laA & 127;
    const int slA = (quad + ((laA >> 7) << 2)) ^ (srA & 7);
    const int offA0 = srA * 128 + (slA << 4);
    const int laB = wn + lr, srB = laB & 127;
    const int slB = (quad + ((laB >> 7) << 2)) ^ (srB & 7);
    const int offB0 = srB * 128 + (slB << 4);
    const char* ldsB = (const char*)lds;

    // epilogue row indices -> LDS (broadcast reads later)
    if (tid < 256) sidx[tid] = indices[m0 + tid];

    // ---- prologue: stage K-tiles 0,1,2 into slots 0,1,2 (12 loads/thread) ----
#pragma unroll
    for (int pt = 0; pt < 3; ++pt) {
        load16(gA0 + pt * 32, dA + pt * 8192);
        load16(gA1 + pt * 32, dA + pt * 8192 + 4096);
        load16(gB0 + pt * 32, dB + pt * 8192);
        load16(gB1 + pt * 32, dB + pt * 8192 + 4096);
    }
    asm volatile("s_waitcnt vmcnt(8)" ::: "memory");  // tile 0 landed (FIFO)
    __builtin_amdgcn_s_barrier();
    asm volatile("" ::: "memory");

    f32x4 acc[8][4] = {};

    for (int tt = 0; tt < NT; tt += 4) {
#pragma unroll
        for (int u = 0; u < 4; ++u) {                // slot of tile t is u
            const int t  = tt + u;
            const int ps = (u + 3) & 3;              // prefetch slot (freed at last barrier)
            const int tf = (t + 3 < NT) ? (t + 3) : (t + 3 - NT);  // wrap: dummy restage, never read
            bf16x8 af[4], bf[4];
            // ---------------- phase 0: mi 0..3 ----------------
#pragma unroll
            for (int mi = 0; mi < 4; ++mi)
                af[mi] = *(const bf16x8*)(ldsB + u * 16384 + offA0 + mi * 2048);
#pragma unroll
            for (int ni = 0; ni < 4; ++ni)
                bf[ni] = *(const bf16x8*)(ldsB + 65536 + u * 16384 + offB0 + ni * 2048);
            load16(gA0 + tf * 32, dA + ps * 8192);
            load16(gA1 + tf * 32, dA + ps * 8192 + 4096);
            __builtin_amdgcn_s_barrier();
            asm volatile("s_waitcnt lgkmcnt(0)" ::: "memory");
            __builtin_amdgcn_s_setprio(1);
#pragma unroll
            for (int mi = 0; mi < 4; ++mi)
#pragma unroll
                for (int ni = 0; ni < 4; ++ni)
                    acc[mi][ni] = __builtin_amdgcn_mfma_f32_16x16x32_bf16(
                        af[mi], bf[ni], acc[mi][ni], 0, 0, 0);
            __builtin_amdgcn_s_setprio(0);
            __builtin_amdgcn_s_barrier();
            asm volatile("" ::: "memory");
            // ---------------- phase 1: mi 4..7 (bf reused) ----------------
#pragma unroll
            for (int mi = 0; mi < 4; ++mi)
                af[mi] = *(const bf16x8*)(ldsB + u * 16384 + offA0 + 8192 + mi * 2048);
            load16(gB0 + tf * 32, dB + ps * 8192);
            load16(gB1 + tf * 32, dB + ps * 8192 + 4096);
            __builtin_amdgcn_s_barrier();
            asm volatile("s_waitcnt lgkmcnt(0)" ::: "memory");
            __builtin_amdgcn_s_setprio(1);
#pragma unroll
            for (int mi = 0; mi < 4; ++mi)
#pragma unroll
                for (int ni = 0; ni < 4; ++ni)
                    acc[4 + mi][ni] = __builtin_amdgcn_mfma_f32_16x16x32_bf16(
                        af[mi], bf[ni], acc[4 + mi][ni], 0, 0, 0);
            __builtin_amdgcn_s_setprio(0);
            // once per K-tile: retire exactly the NEXT tile's 4 loads.
            // outstanding here = tiles t+1,t+2,t+3 (4 each, FIFO).
            asm volatile("s_waitcnt vmcnt(8)" ::: "memory");
            __builtin_amdgcn_s_barrier();
            asm volatile("" ::: "memory");
        }
    }

    // ---- epilogue: D lane layout col=lane&15, row=quad*4+reg (m91-verified);
    // nontemporal scalar stores: output never re-read -> skip RFO, keep L2 clean ----
#pragma unroll
    for (int mi = 0; mi < 8; ++mi) {
#pragma unroll
        for (int r = 0; r < 4; ++r) {
            int lm   = wm + mi * 16 + quad * 4 + r;
            int orow = sidx[lm];
            float* op = out + (size_t)orow * N + n0 + wn + lr;
#pragma unroll
            for (int ni = 0; ni < 4; ++ni)
                __builtin_nontemporal_store(acc[mi][ni][r], op + ni * 16);
        }
    }
}

extern "C" void kernel_launch(void* const* d_in, const int* in_sizes, int n_in,
                              void* d_out, int out_size, void* d_ws, size_t ws_size,
                              hipStream_t stream) {
    const float* input    = (const float*)d_in[0];
    const int*   idx      = (const int*)d_in[1];
    const float* weight   = (const float*)d_in[2];
    const int*   indices  = (const int*)d_in[3];
    const int*   metadata = (const int*)d_in[4];
    float* out = (float*)d_out;

    // workspace layout: A2 (16 MB) | Bbt (16 MB)
    unsigned short* A2  = (unsigned short*)d_ws;
    unsigned short* Bbt = (unsigned short*)((char*)d_ws + (size_t)(16 << 20));

    // merged prep: 4096 decompress + 4096 cast + 4097 zero blocks
    prep<<<O_DIM + (N_TOK * K_ACT / 8) / 256 + O_DIM + 1, 256, 0, stream>>>(
        weight, metadata, idx, input, indices, (uint4*)A2, (uint4*)Bbt,
        (unsigned long long*)out);

    gemm8<<<256, 512, 0, stream>>>(A2, Bbt, indices, out);
}

// Round 6
// 278.037 us; speedup vs baseline: 1.0243x; 1.0243x over previous
//
#include <hip/hip_runtime.h>
#include <hip/hip_bf16.h>
#include <stdint.h>

// Problem constants (from reference)
#define O_DIM   4096
#define I_DIM   2048
#define M_DENSE 8192
#define K_DENSE 4096
#define N_TOK   4096
#define K_ACT   2048

typedef __bf16 bf16x8 __attribute__((ext_vector_type(8)));
typedef float  f32x4  __attribute__((ext_vector_type(4)));

// round-to-nearest-even fp32 -> bf16 bits
__device__ __forceinline__ unsigned f2bf(float f) {
    unsigned u = __builtin_bit_cast(unsigned, f);
    return (u + 0x7FFFu + ((u >> 16) & 1u)) >> 16;
}

// async global->LDS, 16 bytes per lane; LDS dest = wave-uniform base + lane*16
__device__ __forceinline__ void load16(const unsigned short* g, unsigned short* l) {
    __builtin_amdgcn_global_load_lds(
        (__attribute__((address_space(1))) void*)(g),
        (__attribute__((address_space(3))) void*)(l),
        16, 0, 0);
}

// ---------------------------------------------------------------------------
// Merged prep (R5-proven structure, stores reverted to plain/cached — R5
// falsified the RFO theory: FETCH identical with/without nt, dur +3us):
//   blocks [0, O_DIM)            : decompress 2:4 weights -> A2 [O][K_ACT] bf16
//   blocks [O_DIM, O_DIM+4096)   : cast input fp32 -> Bbt bf16
//   blocks [O_DIM+4096, +4097)   : zero INACTIVE dense output rows
// ---------------------------------------------------------------------------
__global__ __launch_bounds__(256) void prep(const float* __restrict__ weight,
                                            const int* __restrict__ metadata,
                                            const int* __restrict__ idx,
                                            const float* __restrict__ input,
                                            const int* __restrict__ indices,
                                            uint4* __restrict__ A2,
                                            uint4* __restrict__ Bbt,
                                            float4* __restrict__ out4) {
    const int CAST_BLKS = (N_TOK * K_ACT / 8) / 256;   // 4096
    int bx = blockIdx.x;
    if (bx >= O_DIM + CAST_BLKS) {
        // ---- zero branch: block b zeroes rows in (indices[b-1], indices[b]) ----
        int b = bx - (O_DIM + CAST_BLKS);               // 0 .. O_DIM
        int lo = (b == 0) ? -1 : indices[b - 1];
        int hi = (b == O_DIM) ? M_DENSE : indices[b];
        for (int row = lo + 1; row < hi; ++row) {
            float4* dst = out4 + (size_t)row * (N_TOK / 4);
            for (int c = threadIdx.x; c < N_TOK / 4; c += 256)
                dst[c] = float4{0.f, 0.f, 0.f, 0.f};
        }
        return;
    }
    if (bx >= O_DIM) {
        // ---- cast branch: fp32 [N_TOK x K_ACT] -> bf16 bits ----
        int gid = (bx - O_DIM) * 256 + threadIdx.x;
        const float4* in = (const float4*)input;
        float4 a = in[2 * gid], b = in[2 * gid + 1];
        uint4 u;
        u.x = f2bf(a.x) | (f2bf(a.y) << 16);
        u.y = f2bf(a.z) | (f2bf(a.w) << 16);
        u.z = f2bf(b.x) | (f2bf(b.y) << 16);
        u.w = f2bf(b.z) | (f2bf(b.w) << 16);
        Bbt[gid] = u;
        return;
    }
    // ---- decompress branch: A2[o][j] = weight value for active col idx[j] ----
    __shared__ int   smeta[I_DIM];
    __shared__ float sw[I_DIM];
    int o = bx;
    const int4*   mrow = (const int4*)(metadata + (size_t)o * I_DIM);
    const float4* wrow = (const float4*)(weight + (size_t)o * I_DIM);
#pragma unroll
    for (int it = 0; it < I_DIM / 4 / 256; ++it) {
        int i = it * 256 + threadIdx.x;
        *(int4*)(smeta + i * 4) = mrow[i];
        *(float4*)(sw + i * 4)  = wrow[i];
    }
    __syncthreads();
    int j0 = threadIdx.x * 8;                            // 256 threads * 8 = K_ACT
    int4 c0 = *(const int4*)(idx + j0);
    int4 c1 = *(const int4*)(idx + j0 + 4);
    int cs[8] = {c0.x, c0.y, c0.z, c0.w, c1.x, c1.y, c1.z, c1.w};
    unsigned r[8];
#pragma unroll
    for (int u = 0; u < 8; ++u) {
        int c = cs[u];
        int g2 = (c >> 2) * 2;
        int pos = c & 3;
        int m0v = smeta[g2], m1v = smeta[g2 + 1];
        float v = (m0v == pos) ? sw[g2] : ((m1v == pos) ? sw[g2 + 1] : 0.0f);
        r[u] = f2bf(v);
    }
    uint4 packed;
    packed.x = r[0] | (r[1] << 16);
    packed.y = r[2] | (r[3] << 16);
    packed.z = r[4] | (r[5] << 16);
    packed.w = r[6] | (r[7] << 16);
    A2[((size_t)o * K_ACT + j0) >> 3] = packed;
}

// ---------------------------------------------------------------------------
// GEMM (REVERT to session-proven 128x128 kernel — ~880 TF, <80us, verified
// SQ_LDS_BANK_CONFLICT=0 at 4 blocks/CU):
//   C[o][t] = sum_j A2[o][j] * Bt[t][j]; rows scattered to out[indices[o]].
// M=4096, N=4096, K=2048. 128x128 tile, BK=64, 4 waves, 16x16x32 bf16 MFMA.
// Why revert: the R1/R5 256²/8-wave/8-phase port measured 800 TF (85.9us)
// at MfmaUtil 31.7% — and fixing its bank conflicts to ZERO (R5) changed
// neither MfmaUtil nor duration, i.e. it is stall-bound on something not
// visible in {MfmaUtil, VALUBusy, HBM, conflicts, occupancy}. The simple
// 2-barrier structure below empirically beats it on this problem.
// Zero-bank-conflict layout: 128B LDS rows span all 32 banks; k-segments
// XOR-swizzled by row&7 (phys slot = seg ^ (row&7)); staging chunk
// f=q*256+t has r=q*32+(t>>3), r&7 = (t>>3)&7 q-INDEPENDENT, so staging
// addresses derive from 2 base pointers + uniform strides.
// ---------------------------------------------------------------------------
__global__ __launch_bounds__(256, 4) void gemm_scatter(
        const unsigned short* __restrict__ A,
        const unsigned short* __restrict__ Bt,
        const int* __restrict__ indices,
        float* __restrict__ out) {
    constexpr int N = N_TOK, K = K_ACT;
    constexpr int TM = 128, TN = 128, BK = 64;
    __shared__ alignas(16) unsigned short sA[TM * BK];   // 16 KB
    __shared__ alignas(16) unsigned short sB[TN * BK];   // 16 KB

    const int t    = threadIdx.x;       // 0..255
    const int wave = t >> 6;            // 0..3
    const int lane = t & 63;
    const int m0 = blockIdx.y * TM;
    const int n0 = blockIdx.x * TN;

    // staging bases: phys slot (t&7) of row r holds global k-seg (t&7)^(r&7)
    const int rbase = t >> 3;                    // row within 32-row band
    const int sseg  = (t & 7) ^ (rbase & 7);     // q-independent source seg
    const unsigned short* gA = A  + (size_t)(m0 + rbase) * K + sseg * 8;
    const unsigned short* gB = Bt + (size_t)(n0 + rbase) * K + sseg * 8;
    unsigned short* lA = sA + wave * 512;        // + q*2048 per band
    unsigned short* lB = sB + wave * 512;

    const int wm   = (wave >> 1) * 64;  // wave's 64x64 quadrant
    const int wn   = (wave & 1) * 64;
    const int quad = lane >> 4;
    const int lr   = lane & 15;
    const int lr7  = lr & 7;
    // fragment rows have row&7 == lr&7; global seg quad -> phys slot quad^lr7,
    // second k-half seg quad|4 -> phys slot ^4 -> element offset ^32.
    const int k0 = (quad ^ lr7) * 8;
    const int k1 = k0 ^ 32;

    f32x4 acc[4][4] = {};

    for (int kk = 0; kk < K; kk += BK) {
        __syncthreads();   // previous compute done before overwriting LDS
#pragma unroll
        for (int q = 0; q < 4; ++q) {
            load16(gA + (size_t)q * (32 * K) + kk, lA + q * 2048);
            load16(gB + (size_t)q * (32 * K) + kk, lB + q * 2048);
        }
        __syncthreads();   // drains vmcnt before barrier

        bf16x8 af[4], bf[4];
        // ---- k-half 0 (k 0..31 of this BK) ----
#pragma unroll
        for (int mi = 0; mi < 4; ++mi)
            af[mi] = *(const bf16x8*)(sA + (wm + mi * 16 + lr) * BK + k0);
#pragma unroll
        for (int ni = 0; ni < 4; ++ni)
            bf[ni] = *(const bf16x8*)(sB + (wn + ni * 16 + lr) * BK + k0);
#pragma unroll
        for (int mi = 0; mi < 4; ++mi)
#pragma unroll
            for (int ni = 0; ni < 4; ++ni)
                acc[mi][ni] = __builtin_amdgcn_mfma_f32_16x16x32_bf16(
                    af[mi], bf[ni], acc[mi][ni], 0, 0, 0);
        // ---- k-half 1 (k 32..63) ----
#pragma unroll
        for (int mi = 0; mi < 4; ++mi)
            af[mi] = *(const bf16x8*)(sA + (wm + mi * 16 + lr) * BK + k1);
#pragma unroll
        for (int ni = 0; ni < 4; ++ni)
            bf[ni] = *(const bf16x8*)(sB + (wn + ni * 16 + lr) * BK + k1);
#pragma unroll
        for (int mi = 0; mi < 4; ++mi)
#pragma unroll
            for (int ni = 0; ni < 4; ++ni)
                acc[mi][ni] = __builtin_amdgcn_mfma_f32_16x16x32_bf16(
                    af[mi], bf[ni], acc[mi][ni], 0, 0, 0);
    }

    // epilogue: D lane layout col=lane&15, row=quad*4+reg (m91-verified);
    // plain cached stores (R5: nt falsified — FETCH unchanged, WRITE up)
#pragma unroll
    for (int mi = 0; mi < 4; ++mi) {
#pragma unroll
        for (int r = 0; r < 4; ++r) {
            int gm = m0 + wm + mi * 16 + quad * 4 + r;
            int orow = indices[gm];
            float* op = out + (size_t)orow * N + n0 + wn + lr;
#pragma unroll
            for (int ni = 0; ni < 4; ++ni)
                op[ni * 16] = acc[mi][ni][r];
        }
    }
}

extern "C" void kernel_launch(void* const* d_in, const int* in_sizes, int n_in,
                              void* d_out, int out_size, void* d_ws, size_t ws_size,
                              hipStream_t stream) {
    const float* input    = (const float*)d_in[0];
    const int*   idx      = (const int*)d_in[1];
    const float* weight   = (const float*)d_in[2];
    const int*   indices  = (const int*)d_in[3];
    const int*   metadata = (const int*)d_in[4];
    float* out = (float*)d_out;

    // workspace layout: A2 (16 MB) | Bbt (16 MB)
    unsigned short* A2  = (unsigned short*)d_ws;
    unsigned short* Bbt = (unsigned short*)((char*)d_ws + (size_t)(16 << 20));

    // merged prep: 4096 decompress + 4096 cast + 4097 zero blocks
    prep<<<O_DIM + (N_TOK * K_ACT / 8) / 256 + O_DIM + 1, 256, 0, stream>>>(
        weight, metadata, idx, input, indices, (uint4*)A2, (uint4*)Bbt, (float4*)out);

    dim3 grid(N_TOK / 128, O_DIM / 128);  // (32, 32)
    gemm_scatter<<<grid, 256, 0, stream>>>(A2, Bbt, indices, out);
}